// Round 4
// baseline (512.268 us; speedup 1.0000x reference)
//
#include <hip/hip_runtime.h>
#include <hip/hip_bf16.h>
#include <math.h>

// LineRWKVBlock: y = (x + sigmoid(x@Wr) * scan(x@Wv)) ; y += y@Wc
// B=16, W=2048, D=1024, decay=0.99.
//
// R6: full m201-template port. R4(8 fine phases, BK=32)=815 TF, R5(coarse
// 2-phase)=731 TF — matches m196/m233: fine interleave is the lever and BK=32
// can't amortize. R6: BK=64, 256^2 tile, 8 waves, 128 KiB dynamic LDS,
// 8 phases per 2 K-tiles:
//   phase = {ds_reads | stage 1 half-tile | bar | lgkm0 | setprio 16 MFMA | bar}
//   stage map: ph0 Q.A1 | ph1 R.B0 | ph2 R.B1 | ph3 R.A0 | ph4 R.A1 | ph5 S.B0
//              | ph6 S.B1 | ph7 S.A0   (P,Q = tiles 2j,2j+1; R,S = 2j+2,2j+3)
//   vmcnt(6) at end of ph3/ph7 only (before barrier: own-drain+bar publishes);
//   ledger: drain-to-6 retires exactly the tile needed next, 3 half-tiles fly.
//   LDS swizzle for 128B rows: slot' = slot ^ (row&7), both-sides
//   (inverse-swizzled global src for linear gload_lds + swizzled ds_read).
//
// ws: WT 6 MiB | Xb 64 | V/y_tmp 64 | R 64 | sl 1 | s_in 1  = 200 MiB

#define MROWS 32768           // B*W
#define NCHUNK 16
#define CHUNKL 128
#define DECAY_F 0.99f
#define OM_F 0.01f

typedef __attribute__((ext_vector_type(8))) short short8;   // 8 bf16 (4 VGPRs)
typedef __attribute__((ext_vector_type(4))) float floatx4;

using bf16 = __hip_bfloat16;
using bf162 = __hip_bfloat162;

// async global->LDS, 16B per lane; lds base wave-uniform, HW scatters lane i at
// base + i*16.
__device__ __forceinline__ void async_copy16(const void* g, void* l) {
  __builtin_amdgcn_global_load_lds(
      (const __attribute__((address_space(1))) unsigned int*)g,
      (__attribute__((address_space(3))) unsigned int*)l, 16, 0, 0);
}

#define S_BARRIER() asm volatile("s_barrier" ::: "memory")
#define VMCNT6()                                                               \
  do {                                                                         \
    asm volatile("s_waitcnt vmcnt(6)" ::: "memory");                           \
    __builtin_amdgcn_sched_barrier(0);                                         \
  } while (0)
#define VMCNT0()                                                               \
  do {                                                                         \
    asm volatile("s_waitcnt vmcnt(0)" ::: "memory");                           \
    __builtin_amdgcn_sched_barrier(0);                                         \
  } while (0)
#define LGKM0()                                                                \
  do {                                                                         \
    asm volatile("s_waitcnt lgkmcnt(0)" ::: "memory");                         \
    __builtin_amdgcn_sched_barrier(0);                                         \
  } while (0)

// ---------------- kernel 1: x fp32 -> bf16 ----------------
__global__ void prep_x(const float* __restrict__ X, bf16* __restrict__ Xb) {
  const int idx = blockIdx.x * 256 + threadIdx.x;   // 8388608 float4-groups
  const float4 v = ((const float4*)X)[idx];
  union { ushort4 u; bf16 h[4]; } pk;
  pk.h[0] = __float2bfloat16(v.x);
  pk.h[1] = __float2bfloat16(v.y);
  pk.h[2] = __float2bfloat16(v.z);
  pk.h[3] = __float2bfloat16(v.w);
  ((ushort4*)Xb)[idx] = pk.u;
}

// ---------------- kernel 2: weight transpose + bf16 cast ----------------
// WT rows 0..1023 = Wv^T, 1024..2047 = Wr^T, 2048..3071 = Wc^T ; WT[n][k]
__global__ void prep_weights(const float* __restrict__ Wv,
                             const float* __restrict__ Wr,
                             const float* __restrict__ Wc,
                             bf16* __restrict__ WT) {
  __shared__ float tile[32][33];
  const int bk = blockIdx.x * 32;   // k block
  const int bn = blockIdx.y * 32;   // global n block (0..3071)
  const float* src;
  int nbase = bn;
  if (bn < 1024)      { src = Wv; }
  else if (bn < 2048) { src = Wr; nbase = bn - 1024; }
  else                { src = Wc; nbase = bn - 2048; }
  const int tx = threadIdx.x;       // 32
  const int ty = threadIdx.y;       // 8
  #pragma unroll
  for (int i = ty; i < 32; i += 8)
    tile[i][tx] = src[(size_t)(bk + i) * 1024 + nbase + tx];  // tile[k][n]
  __syncthreads();
  #pragma unroll
  for (int i = ty; i < 32; i += 8)
    WT[(size_t)(bn + i) * 1024 + bk + tx] = __float2bfloat16(tile[tx][i]);
}

// ---------------- kernels 3/7: 256^2 BK=64 8-phase GEMM (m201 port) --------
// MODE 0: v/r GEMM  -> Vout bf16 (nt<4), Rout = sigmoid (nt>=4); N=2048
// MODE 1: mix GEMM  -> Fout fp32 = bf16(A)[o] + acc ; N=1024
//
// Dynamic LDS 128 KiB: buf0 { A0@0 | A1@16384 | B0@32768 | B1@49152 },
// buf1 @ +65536. Region = [128 rows][64 bf16] = 16 KiB; rows are 128 B
// (= all 32 banks), swizzle slot' = slot ^ (row&7) on 16B slots.

#define MFMA16(MB, FA)                                                         \
  __builtin_amdgcn_s_setprio(1);                                               \
  _Pragma("unroll")                                                            \
  for (int nf = 0; nf < 4; ++nf) {                                             \
    acc[MB][nf] = __builtin_amdgcn_mfma_f32_16x16x32_bf16(                     \
        FA[0][0], fb[nf][0], acc[MB][nf], 0, 0, 0);                            \
    acc[MB + 1][nf] = __builtin_amdgcn_mfma_f32_16x16x32_bf16(                 \
        FA[1][0], fb[nf][0], acc[MB + 1][nf], 0, 0, 0);                        \
  }                                                                            \
  _Pragma("unroll")                                                            \
  for (int nf = 0; nf < 4; ++nf) {                                             \
    acc[MB][nf] = __builtin_amdgcn_mfma_f32_16x16x32_bf16(                     \
        FA[0][1], fb[nf][1], acc[MB][nf], 0, 0, 0);                            \
    acc[MB + 1][nf] = __builtin_amdgcn_mfma_f32_16x16x32_bf16(                 \
        FA[1][1], fb[nf][1], acc[MB + 1][nf], 0, 0, 0);                        \
  }                                                                            \
  __builtin_amdgcn_s_setprio(0);

#define READA(FA, MB, PTR)                                                     \
  FA[0][0] = *(const short8*)((PTR) + (MB) * 2048 + lk0);                      \
  FA[0][1] = *(const short8*)((PTR) + (MB) * 2048 + lk1);                      \
  FA[1][0] = *(const short8*)((PTR) + ((MB) + 1) * 2048 + lk0);                \
  FA[1][1] = *(const short8*)((PTR) + ((MB) + 1) * 2048 + lk1);

#define READB(PTR)                                                             \
  _Pragma("unroll")                                                            \
  for (int nf = 0; nf < 4; ++nf) {                                             \
    fb[nf][0] = *(const short8*)((PTR) + nf * 2048 + lk0);                     \
    fb[nf][1] = *(const short8*)((PTR) + nf * 2048 + lk1);                     \
  }

// stage one 16 KiB region (128 rows x 128 B) = 2 gload_lds of 8 KiB
#define STAGE(GP, LOFF)                                                        \
  do {                                                                         \
    async_copy16((GP), lds + (LOFF) + wb);                                     \
    async_copy16((GP) + (size_t)64 * 2048, lds + (LOFF) + 8192 + wb);          \
  } while (0)

template <int MODE>
__global__ __launch_bounds__(512, 2) void gemm8(const bf16* __restrict__ Ab,
                                                const bf16* __restrict__ Bw,
                                                bf16* __restrict__ Vout,
                                                bf16* __restrict__ Rout,
                                                float* __restrict__ Fout) {
  extern __shared__ char lds[];
  constexpr int NTN = (MODE == 0) ? 8 : 4;

  // bijective XCD-chunk swizzle (nwg % 8 == 0)
  const int nwg = gridDim.x;
  const int id = blockIdx.x;
  const int wg = (id & 7) * (nwg >> 3) + (id >> 3);
  const int mt = wg / NTN, nt = wg % NTN;
  const int m0 = mt * 256, n0 = nt * 256;

  const int t = threadIdx.x;
  const int l = t & 63, w = t >> 6;          // 8 waves
  const int wm = w >> 2, wn = w & 3;         // 2 (M) x 4 (N) wave grid
  const int wb = w * 1024;                   // wave's slice per gload_lds

  // ---- staging: LDS dest linear; global source inverse-swizzled.
  // dst(lane) row = s*64 + w*8 + (l>>3), slot = l&7 ; G-col-slot = slot^(row&7)
  const int sgrow = w * 8 + (l >> 3);
  const int sgcol = ((l & 7) ^ ((l >> 3) & 7)) * 16;
  const char* gA0 = (const char*)Ab + (size_t)(m0 + sgrow) * 2048 + sgcol;
  const char* gA1 = gA0 + (size_t)128 * 2048;
  const char* gB0 = (const char*)Bw + (size_t)(n0 + sgrow) * 2048 + sgcol;
  const char* gB1 = gB0 + (size_t)128 * 2048;

  // ---- read-side: frag (row, kslot = ks*4+qd) at row*128 + (kslot^(row&7))*16
  const int ll = l & 15, qd = l >> 4;
  const int arow = ll * 128;
  const int lk0 = ((qd ^ (ll & 7)) << 4);
  const int lk1 = (((4 | qd) ^ (ll & 7)) << 4);
  const char* pAP = lds + wm * 16384 + arow;                              // buf0 A
  const char* pBP = lds + 32768 + (wn >> 1) * 16384 + (wn & 1) * 8192 + arow;
  const char* pAQ = pAP + 65536;                                          // buf1
  const char* pBQ = pBP + 65536;

  floatx4 acc[8][4];
  #pragma unroll
  for (int i = 0; i < 8; ++i)
    #pragma unroll
    for (int j = 0; j < 4; ++j) acc[i][j] = (floatx4){0.f, 0.f, 0.f, 0.f};

  short8 fa01[2][2], fa23[2][2], fa45[2][2], fa67[2][2], fb[4][2];

  // ---- prologue: T0 {B0,B1,A0,A1} -> buf0 ; T1 {B0,B1,A0} -> buf1
  STAGE(gB0, 32768);         gB0 += 128;   // T0.B0
  STAGE(gB1, 49152);         gB1 += 128;   // T0.B1
  STAGE(gA0, 0);             gA0 += 128;   // T0.A0
  STAGE(gA1, 16384);         gA1 += 128;   // T0.A1
  STAGE(gB0, 65536 + 32768); gB0 += 128;   // T1.B0
  STAGE(gB1, 65536 + 49152); gB1 += 128;   // T1.B1
  STAGE(gA0, 65536);         gA0 += 128;   // T1.A0
  VMCNT6();        // T0 landed; T1 {B0,B1,A0} in flight
  S_BARRIER();

  // ---- main loop: 8 iters x 2 K-tiles (BK=64); iter j: P=2j(buf0), Q=2j+1(buf1)
  for (int j = 0; j < 8; ++j) {
    const bool full = (j < 7);
    // ========== P in buf0 ==========
    // ph0: read fb(P)+fa01(P); stage Q.A1 -> buf1.A1
    READB(pBP);
    READA(fa01, 0, pAP);
    STAGE(gA1, 65536 + 16384); gA1 += 128;
    S_BARRIER(); LGKM0();
    MFMA16(0, fa01);
    S_BARRIER();
    // ph1: read fa23+fa45; stage R.B0 -> buf0.B0 (B consumed ph0)
    READA(fa23, 2, pAP);
    READA(fa45, 4, pAP);
    if (full) { STAGE(gB0, 32768); gB0 += 128; }
    S_BARRIER(); LGKM0();
    MFMA16(2, fa23);
    S_BARRIER();
    // ph2: read fa67; stage R.B1
    READA(fa67, 6, pAP);
    if (full) { STAGE(gB1, 49152); gB1 += 128; }
    S_BARRIER(); LGKM0();
    MFMA16(4, fa45);
    S_BARRIER();
    // ph3: stage R.A0 (A reads all issued by ph2); counted drain; 1 barrier
    if (full) { STAGE(gA0, 0); gA0 += 128; }
    MFMA16(6, fa67);
    if (full) { VMCNT6(); } else { VMCNT0(); }   // Q fully landed after barrier
    S_BARRIER();
    // ========== Q in buf1 ==========
    // ph4: read fb(Q)+fa01(Q); stage R.A1 -> buf0.A1
    READB(pBQ);
    READA(fa01, 0, pAQ);
    if (full) { STAGE(gA1, 16384); gA1 += 128; }
    S_BARRIER(); LGKM0();
    MFMA16(0, fa01);
    S_BARRIER();
    // ph5: read fa23+fa45; stage S.B0 -> buf1.B0
    READA(fa23, 2, pAQ);
    READA(fa45, 4, pAQ);
    if (full) { STAGE(gB0, 65536 + 32768); gB0 += 128; }
    S_BARRIER(); LGKM0();
    MFMA16(2, fa23);
    S_BARRIER();
    // ph6: read fa67; stage S.B1
    READA(fa67, 6, pAQ);
    if (full) { STAGE(gB1, 65536 + 49152); gB1 += 128; }
    S_BARRIER(); LGKM0();
    MFMA16(4, fa45);
    S_BARRIER();
    // ph7: stage S.A0; counted drain -> next iter's P landed after barrier
    if (full) { STAGE(gA0, 65536); gA0 += 128; }
    MFMA16(6, fa67);
    if (full) { VMCNT6(); S_BARRIER(); }
  }

  // ---- epilogue: C/D layout col = lane&15, row = (lane>>4)*4 + reg
  const int orow0 = m0 + wm * 128 + (l >> 4) * 4;
  const int ocol = n0 + wn * 64 + ll;
  if constexpr (MODE == 0) {
    const bool isr = (n0 >= 1024);
    bf16* outp = isr ? Rout : Vout;
    const int oc = isr ? (ocol - 1024) : ocol;
    #pragma unroll
    for (int mf = 0; mf < 8; ++mf) {
      #pragma unroll
      for (int i = 0; i < 4; ++i) {
        const size_t ro = (size_t)(orow0 + mf * 16 + i) * 1024 + oc;
        #pragma unroll
        for (int nf = 0; nf < 4; ++nf) {
          float cv = acc[mf][nf][i];
          if (isr) cv = 1.0f / (1.0f + __expf(-cv));
          outp[ro + nf * 16] = __float2bfloat16(cv);
        }
      }
    }
  } else {
    #pragma unroll
    for (int mf = 0; mf < 8; ++mf) {
      #pragma unroll
      for (int i = 0; i < 4; ++i) {
        const size_t ro = (size_t)(orow0 + mf * 16 + i) * 1024 + ocol;
        #pragma unroll
        for (int nf = 0; nf < 4; ++nf) {
          const size_t o = ro + nf * 16;
          Fout[o] = __bfloat162float(Ab[o]) + acc[mf][nf][i];
        }
      }
    }
  }
}

// ---------------- kernel 4: chunk-local decayed sums ----------------
__global__ void scan_partial(const bf16* __restrict__ V, float* __restrict__ sl) {
  const int idx = blockIdx.x * 256 + threadIdx.x;   // 131072 = B*NCHUNK*(D/2)
  const int d2 = idx & 511;
  const int c = (idx >> 9) & 15;
  const int b = idx >> 13;
  const bf162* V2 = (const bf162*)V;
  const size_t base = (size_t)(b * 2048 + c * 128) * 512 + d2;
  float s0 = 0.f, s1 = 0.f;
  for (int w = 0; w < CHUNKL; ++w) {
    const bf162 v = V2[base + (size_t)w * 512];
    s0 = DECAY_F * s0 + OM_F * __bfloat162float(v.x);
    s1 = DECAY_F * s1 + OM_F * __bfloat162float(v.y);
  }
  const int o = (b * 16 + c) * 1024 + d2 * 2;
  sl[o] = s0;
  sl[o + 1] = s1;
}

// ---------------- kernel 5: chunk-level scan ----------------
__global__ void scan_chunk(const float* __restrict__ state,
                           const float* __restrict__ sl,
                           float* __restrict__ sin_,
                           float* __restrict__ state_out,
                           float decayL) {
  const int idx = blockIdx.x * 256 + threadIdx.x;   // 16384 = B*D
  const int d = idx & 1023;
  const int b = idx >> 10;
  float s = state[idx];
  #pragma unroll
  for (int c = 0; c < NCHUNK; ++c) {
    const int o = (b * 16 + c) * 1024 + d;
    sin_[o] = s;
    s = decayL * s + sl[o];
  }
  state_out[idx] = s;
}

// ---------------- kernel 6: y_tmp = xb + r*s (in place over V) ----------
__global__ void scan_apply(const bf16* __restrict__ Xb,
                           const bf16* __restrict__ R,
                           const float* __restrict__ sin_,
                           bf16* __restrict__ VY) {
  const int idx = blockIdx.x * 256 + threadIdx.x;   // 131072
  const int d2 = idx & 511;
  const int c = (idx >> 9) & 15;
  const int b = idx >> 13;
  const bf162* R2 = (const bf162*)R;
  const bf162* X2 = (const bf162*)Xb;
  bf162* VY2 = (bf162*)VY;
  const size_t base = (size_t)(b * 2048 + c * 128) * 512 + d2;
  const int so = (b * 16 + c) * 1024 + d2 * 2;
  float s0 = sin_[so], s1 = sin_[so + 1];
  for (int w = 0; w < CHUNKL; ++w) {
    const size_t off = base + (size_t)w * 512;
    const bf162 v = VY2[off];
    const bf162 r = R2[off];
    const bf162 xx = X2[off];
    s0 = DECAY_F * s0 + OM_F * __bfloat162float(v.x);
    s1 = DECAY_F * s1 + OM_F * __bfloat162float(v.y);
    const float y0 = __bfloat162float(xx.x) + __bfloat162float(r.x) * s0;
    const float y1 = __bfloat162float(xx.y) + __bfloat162float(r.y) * s1;
    bf162 o;
    o.x = __float2bfloat16(y0);
    o.y = __float2bfloat16(y1);
    VY2[off] = o;
  }
}

extern "C" void kernel_launch(void* const* d_in, const int* in_sizes, int n_in,
                              void* d_out, int out_size, void* d_ws, size_t ws_size,
                              hipStream_t stream) {
  const float* x     = (const float*)d_in[0];
  const float* state = (const float*)d_in[1];
  const float* Wv    = (const float*)d_in[2];
  const float* Wr    = (const float*)d_in[3];
  const float* Wc    = (const float*)d_in[4];

  float* y_out = (float*)d_out;
  float* state_out = y_out + (size_t)MROWS * 1024;

  char* ws = (char*)d_ws;
  bf16* WT   = (bf16*)ws;                                    // 6 MiB
  bf16* Xb   = (bf16*)(ws + ((size_t)6 << 20));              // 64 MiB
  bf16* Vbuf = (bf16*)(ws + ((size_t)70 << 20));             // 64 MiB (also y_tmp)
  bf16* Rbuf = (bf16*)(ws + ((size_t)134 << 20));            // 64 MiB
  float* sl  = (float*)(ws + ((size_t)198 << 20));           // 1 MiB
  float* sin_ = (float*)(ws + ((size_t)199 << 20));          // 1 MiB
  bf16* WcT = WT + (size_t)2048 * 1024;

  const float decayL = (float)pow(0.99, (double)CHUNKL);

  // one-time: allow 128 KiB dynamic LDS (host-side config, not a stream op)
  static bool g_cfg = false;
  if (!g_cfg) {
    auto kf0 = gemm8<0>;
    auto kf1 = gemm8<1>;
    (void)hipFuncSetAttribute((const void*)kf0,
                              hipFuncAttributeMaxDynamicSharedMemorySize, 131072);
    (void)hipFuncSetAttribute((const void*)kf1,
                              hipFuncAttributeMaxDynamicSharedMemorySize, 131072);
    g_cfg = true;
  }

  prep_x<<<32768, 256, 0, stream>>>(x, Xb);
  prep_weights<<<dim3(32, 96), dim3(32, 8), 0, stream>>>(Wv, Wr, Wc, WT);
  gemm8<0><<<1024, 512, 131072, stream>>>(Xb, WT, Vbuf, Rbuf, nullptr);
  scan_partial<<<512, 256, 0, stream>>>(Vbuf, sl);
  scan_chunk<<<64, 256, 0, stream>>>(state, sl, sin_, state_out, decayL);
  scan_apply<<<512, 256, 0, stream>>>(Xb, Rbuf, sin_, Vbuf);
  gemm8<1><<<512, 512, 131072, stream>>>(Vbuf, WcT, nullptr, nullptr, y_out);
}